// Round 1
// baseline (465.086 us; speedup 1.0000x reference)
//
#include <hip/hip_runtime.h>
#include <stdint.h>

typedef __attribute__((ext_vector_type(4))) float f32x4;
typedef __attribute__((ext_vector_type(8))) short bf16x8;

__device__ __forceinline__ unsigned short f2bf(float f) {
  union { float f; uint32_t u; } a; a.f = f;
  uint32_t u = a.u;
  uint32_t r = (u + 0x7FFFu + ((u >> 16) & 1u)) >> 16;
  return (unsigned short)r;
}

// Pack [x | h] -> bf16 A[4096][4096] row-major (K = IN(2048) then H(2048))
__global__ void pack_a_kernel(const float4* __restrict__ x, const float4* __restrict__ hh,
                              ushort4* __restrict__ A) {
  const int total = 4096 * 1024;  // quads (4096 rows x 1024 float4/row)
  for (int q = blockIdx.x * blockDim.x + threadIdx.x; q < total; q += gridDim.x * blockDim.x) {
    int row = q >> 10, cq = q & 1023;
    float4 v = (cq < 512) ? x[row * 512 + cq] : hh[row * 512 + (cq - 512)];
    ushort4 o; o.x = f2bf(v.x); o.y = f2bf(v.y); o.z = f2bf(v.z); o.w = f2bf(v.w);
    A[q] = o;
  }
}

// Pack 8 weight mats -> bf16 Wp[8192][4096], gate-interleaved rows:
// packed row p: gate=(p>>4)&3, h=((p>>6)<<4)|(p&15); cols 0..2047 = Wx_gate[h][:], 2048.. = Wh_gate[h][:]
__global__ void pack_w_kernel(const float* __restrict__ Wii, const float* __restrict__ Wif,
                              const float* __restrict__ Wig, const float* __restrict__ Wio,
                              const float* __restrict__ Whi, const float* __restrict__ Whf,
                              const float* __restrict__ Whg, const float* __restrict__ Who,
                              ushort4* __restrict__ Wp) {
  const int total = 8192 * 1024;  // quads
  for (int q = blockIdx.x * blockDim.x + threadIdx.x; q < total; q += gridDim.x * blockDim.x) {
    int p = q >> 10, kq = q & 1023;
    int gate = (p >> 4) & 3;
    int hrow = ((p >> 6) << 4) | (p & 15);
    const float* src;
    if (kq < 512) src = (gate == 0) ? Wii : (gate == 1) ? Wif : (gate == 2) ? Wig : Wio;
    else          src = (gate == 0) ? Whi : (gate == 1) ? Whf : (gate == 2) ? Whg : Who;
    const float4 v = *(const float4*)&src[(size_t)hrow * 2048 + ((kq & 511) << 2)];
    ushort4 o; o.x = f2bf(v.x); o.y = f2bf(v.y); o.z = f2bf(v.z); o.w = f2bf(v.w);
    Wp[q] = o;
  }
}

// GEMM C[4096][8192] = A[4096][4096] x Wp[8192][4096]^T with fused LSTM epilogue.
// Block: 128 rows x 128 packed-cols (= 32 h-cols x 4 gates). 4 waves 2x2, per-wave 64x64.
// N-fragment index within a wave's 64 packed-cols == gate index (thanks to packing).
__global__ __launch_bounds__(256)
void lstm_gemm_kernel(const ushort* __restrict__ A, const ushort* __restrict__ Wp,
                      const float* __restrict__ c,
                      const float* __restrict__ bii, const float* __restrict__ bif_,
                      const float* __restrict__ big_, const float* __restrict__ bio_,
                      const float* __restrict__ bhi, const float* __restrict__ bhf,
                      const float* __restrict__ bhg, const float* __restrict__ bho,
                      float* __restrict__ out) {
  __shared__ ushort As[128 * 64];
  __shared__ ushort Bs[128 * 64];
  const int tid = threadIdx.x;
  const int lane = tid & 63, wid = tid >> 6;
  const int bm = blockIdx.x >> 6, bn = blockIdx.x & 63;  // 32 x 64 blocks
  const int wm = wid >> 1, wn = wid & 1;

  f32x4 acc[4][4];
#pragma unroll
  for (int i = 0; i < 4; i++)
#pragma unroll
    for (int j = 0; j < 4; j++) acc[i][j] = (f32x4){0.f, 0.f, 0.f, 0.f};

  // Staging: per global_load_lds inst, wave w loads 8 rows (64 lanes x 16B).
  // dest byte = base(i,w) + lane*16 -> row = i*32 + w*8 + lane/8, colchunk = lane%8.
  const ushort* aPtr = A  + (size_t)(bm * 128 + wid * 8 + (lane >> 3)) * 4096 + (lane & 7) * 8;
  const ushort* bPtr = Wp + (size_t)(bn * 128 + wid * 8 + (lane >> 3)) * 4096 + (lane & 7) * 8;
  ushort* aDst = (ushort*)As + wid * 512;  // + i*2048 elems
  ushort* bDst = (ushort*)Bs + wid * 512;

  const int laneRow = lane & 15;
  const int laneK = (lane >> 4) * 8;

  for (int k0 = 0; k0 < 4096; k0 += 64) {
#pragma unroll
    for (int i = 0; i < 4; i++) {
      __builtin_amdgcn_global_load_lds(
          (const __attribute__((address_space(1))) void*)(aPtr + (size_t)i * 32 * 4096 + k0),
          (__attribute__((address_space(3))) void*)(aDst + i * 2048), 16, 0, 0);
      __builtin_amdgcn_global_load_lds(
          (const __attribute__((address_space(1))) void*)(bPtr + (size_t)i * 32 * 4096 + k0),
          (__attribute__((address_space(3))) void*)(bDst + i * 2048), 16, 0, 0);
    }
    __syncthreads();
#pragma unroll
    for (int kk = 0; kk < 2; kk++) {
      bf16x8 af[4], bfr[4];
#pragma unroll
      for (int mi = 0; mi < 4; mi++)
        af[mi] = *(const bf16x8*)&As[(wm * 64 + mi * 16 + laneRow) * 64 + kk * 32 + laneK];
#pragma unroll
      for (int ni = 0; ni < 4; ni++)
        bfr[ni] = *(const bf16x8*)&Bs[(wn * 64 + ni * 16 + laneRow) * 64 + kk * 32 + laneK];
#pragma unroll
      for (int mi = 0; mi < 4; mi++)
#pragma unroll
        for (int ni = 0; ni < 4; ni++)
          acc[mi][ni] = __builtin_amdgcn_mfma_f32_16x16x32_bf16(af[mi], bfr[ni], acc[mi][ni], 0, 0, 0);
    }
    __syncthreads();
  }

  // Fused LSTM epilogue: acc[mi][gate][r] all live in this lane for (row, hcol).
  const int hcol = (bn * 2 + wn) * 16 + laneRow;
  const float bI = bii[hcol] + bhi[hcol];
  const float bF = bif_[hcol] + bhf[hcol];
  const float bG = big_[hcol] + bhg[hcol];
  const float bO = bio_[hcol] + bho[hcol];
  const int rbase = bm * 128 + wm * 64 + ((lane >> 4) << 2);
#pragma unroll
  for (int mi = 0; mi < 4; mi++) {
#pragma unroll
    for (int r = 0; r < 4; r++) {
      const int row = rbase + mi * 16 + r;
      const float ii = acc[mi][0][r] + bI;
      const float ff = acc[mi][1][r] + bF;
      const float gg = acc[mi][2][r] + bG;
      const float oo = acc[mi][3][r] + bO;
      const float iv = 1.f / (1.f + __expf(-ii));
      const float fv = 1.f / (1.f + __expf(-ff));
      const float gv = tanhf(gg);
      const float ov = 1.f / (1.f + __expf(-oo));
      const float cv = c[(size_t)row * 2048 + hcol];
      const float cn = fv * cv + iv * gv;
      const float hn = ov * tanhf(cn);
      out[(size_t)row * 2048 + hcol] = hn;                        // h_new
      out[(size_t)8388608 + (size_t)row * 2048 + hcol] = cn;      // c_new
    }
  }
}

extern "C" void kernel_launch(void* const* d_in, const int* in_sizes, int n_in,
                              void* d_out, int out_size, void* d_ws, size_t ws_size,
                              hipStream_t stream) {
  const float* x = (const float*)d_in[0];
  const float* h = (const float*)d_in[1];
  const float* c = (const float*)d_in[2];
  const float* Wii = (const float*)d_in[3];  const float* bii = (const float*)d_in[4];
  const float* Wif = (const float*)d_in[5];  const float* bif_ = (const float*)d_in[6];
  const float* Wig = (const float*)d_in[7];  const float* big_ = (const float*)d_in[8];
  const float* Wio = (const float*)d_in[9];  const float* bio_ = (const float*)d_in[10];
  const float* Whi = (const float*)d_in[11]; const float* bhi = (const float*)d_in[12];
  const float* Whf = (const float*)d_in[13]; const float* bhf = (const float*)d_in[14];
  const float* Whg = (const float*)d_in[15]; const float* bhg = (const float*)d_in[16];
  const float* Who = (const float*)d_in[17]; const float* bho = (const float*)d_in[18];

  ushort* Abf = (ushort*)d_ws;                    // 4096*4096 bf16 = 33.5 MB
  ushort* Wpk = Abf + (size_t)4096 * 4096;        // 8192*4096 bf16 = 67 MB
  float* out = (float*)d_out;

  pack_a_kernel<<<2048, 256, 0, stream>>>((const float4*)x, (const float4*)h, (ushort4*)Abf);
  pack_w_kernel<<<2048, 256, 0, stream>>>(Wii, Wif, Wig, Wio, Whi, Whf, Whg, Who, (ushort4*)Wpk);
  lstm_gemm_kernel<<<2048, 256, 0, stream>>>(Abf, Wpk, c,
                                             bii, bif_, big_, bio_, bhi, bhf, bhg, bho, out);
}

// Round 2
// 406.900 us; speedup vs baseline: 1.1430x; 1.1430x over previous
//
#include <hip/hip_runtime.h>
#include <stdint.h>

typedef __attribute__((ext_vector_type(4))) float f32x4;
typedef __attribute__((ext_vector_type(8))) short bf16x8;

__device__ __forceinline__ unsigned short f2bf(float f) {
  union { float f; uint32_t u; } a; a.f = f;
  uint32_t u = a.u;
  uint32_t r = (u + 0x7FFFu + ((u >> 16) & 1u)) >> 16;
  return (unsigned short)r;
}

// Pack [x | h] -> bf16 A[4096][4096] row-major (K = IN(2048) then H(2048))
__global__ void pack_a_kernel(const float4* __restrict__ x, const float4* __restrict__ hh,
                              ushort4* __restrict__ A) {
  const int total = 4096 * 1024;
  for (int q = blockIdx.x * blockDim.x + threadIdx.x; q < total; q += gridDim.x * blockDim.x) {
    int row = q >> 10, cq = q & 1023;
    float4 v = (cq < 512) ? x[row * 512 + cq] : hh[row * 512 + (cq - 512)];
    ushort4 o; o.x = f2bf(v.x); o.y = f2bf(v.y); o.z = f2bf(v.z); o.w = f2bf(v.w);
    A[q] = o;
  }
}

// Pack 8 weight mats -> bf16 Wp[8192][4096], gate-interleaved rows:
// packed row p: gate=(p>>4)&3, h=((p>>6)<<4)|(p&15); cols 0..2047 = Wx_gate[h][:], 2048.. = Wh_gate[h][:]
__global__ void pack_w_kernel(const float* __restrict__ Wii, const float* __restrict__ Wif,
                              const float* __restrict__ Wig, const float* __restrict__ Wio,
                              const float* __restrict__ Whi, const float* __restrict__ Whf,
                              const float* __restrict__ Whg, const float* __restrict__ Who,
                              ushort4* __restrict__ Wp) {
  const int total = 8192 * 1024;
  for (int q = blockIdx.x * blockDim.x + threadIdx.x; q < total; q += gridDim.x * blockDim.x) {
    int p = q >> 10, kq = q & 1023;
    int gate = (p >> 4) & 3;
    int hrow = ((p >> 6) << 4) | (p & 15);
    const float* src;
    if (kq < 512) src = (gate == 0) ? Wii : (gate == 1) ? Wif : (gate == 2) ? Wig : Wio;
    else          src = (gate == 0) ? Whi : (gate == 1) ? Whf : (gate == 2) ? Whg : Who;
    const float4 v = *(const float4*)&src[(size_t)hrow * 2048 + ((kq & 511) << 2)];
    ushort4 o; o.x = f2bf(v.x); o.y = f2bf(v.y); o.z = f2bf(v.z); o.w = f2bf(v.w);
    Wp[q] = o;
  }
}

// Deep-pipelined GEMM: C[4096][8192] = A x Wp^T, fused LSTM epilogue.
// Tile 128(M) x 256(Npacked), BK=64, 8 waves (2Mx4N), 3-deep LDS pipeline,
// counted vmcnt(6), T2 XOR-swizzle, T5 setprio.
#define GLD(srcp, dstE) \
  __builtin_amdgcn_global_load_lds((const __attribute__((address_space(1))) void*)(srcp), \
      (__attribute__((address_space(3))) void*)(&smem[dstE]), 16, 0, 0)

__global__ __launch_bounds__(512, 1)
void lstm_gemm_kernel(const ushort* __restrict__ A, const ushort* __restrict__ Wp,
                      const float* __restrict__ c,
                      const float* __restrict__ bii, const float* __restrict__ bif_,
                      const float* __restrict__ big_, const float* __restrict__ bio_,
                      const float* __restrict__ bhi, const float* __restrict__ bhf,
                      const float* __restrict__ bhg, const float* __restrict__ bho,
                      float* __restrict__ out) {
  // 3 buffers x (A 128x64 + B 256x64) bf16 = 3 x 24576 elems = 147456 B
  __shared__ ushort smem[73728];
  const int tid = threadIdx.x;
  const int lane = tid & 63, w = tid >> 6;
  const int wm = w >> 2, wn = w & 3;

  // XCD-aware bijective block swizzle (1024 blocks, 8 XCDs)
  const int bid = blockIdx.x;
  const int wg = (bid & 7) * 128 + (bid >> 3);
  const int bm = wg >> 5, bn = wg & 31;

  const int laneRow = lane & 15, lane16 = lane >> 4;
  const int swz = (lane & 7) << 4;  // == (row&7)<<4 for every frag row this lane reads
  const int colE0 = (((lane16 << 4)) ^ swz) >> 1;        // elem col, kk=0
  const int colE1 = ((64 | (lane16 << 4)) ^ swz) >> 1;   // elem col, kk=1

  // Staging: per global_load_lds, lane l -> LDS row base+ (l>>3), slot (l&7).
  // Physical slot s at row r holds logical chunk s ^ (r&7) -> pre-swizzle global source.
  const int chunk = ((lane & 7) ^ ((lane >> 3) & 7)) << 3;
  const ushort* aSrc = A  + (size_t)(bm * 128 + w * 16 + (lane >> 3)) * 4096 + chunk;
  const ushort* bSrc = Wp + (size_t)(bn * 256 + w * 32 + (lane >> 3)) * 4096 + chunk;
  const int aDstE = w * 1024;          // elems; + j*512 + buf
  const int bDstE = 8192 + w * 2048;   // elems; + j*512 + buf

  f32x4 acc[4][4];
#pragma unroll
  for (int i = 0; i < 4; i++)
#pragma unroll
    for (int j = 0; j < 4; j++) acc[i][j] = (f32x4){0.f, 0.f, 0.f, 0.f};

  const int aRow = (wm * 64 + laneRow) * 64;         // + mi*1024 + colE
  const int bRow = 8192 + (wn * 64 + laneRow) * 64;  // + ni*1024 + colE

  // Prologue: stage tiles 0 and 1 (6 insts each, per wave)
#pragma unroll
  for (int tt = 0; tt < 2; ++tt) {
    const int sB = tt * 24576, kO = tt * 64;
    GLD(aSrc + kO, sB + aDstE);
    GLD(aSrc + 8 * 4096 + kO, sB + aDstE + 512);
    GLD(bSrc + kO, sB + bDstE);
    GLD(bSrc + 8 * 4096 + kO, sB + bDstE + 512);
    GLD(bSrc + 16 * 4096 + kO, sB + bDstE + 1024);
    GLD(bSrc + 24 * 4096 + kO, sB + bDstE + 1536);
  }
  asm volatile("s_waitcnt vmcnt(6)" ::: "memory");  // tile 0 complete
  __builtin_amdgcn_s_barrier();
  __builtin_amdgcn_sched_barrier(0);

  int bufE = 0, sBufE = 49152, kOff = 128;
#pragma unroll 1
  for (int t = 0; t < 64; ++t) {
    const bool doStage = (t < 62);
    bf16x8 af[4], bf[4];
    // ---- phase 0: stage A(j0,j1) of tile t+2 ; compute kk0, ni 0-1
    if (doStage) {
      GLD(aSrc + kOff, sBufE + aDstE);
      GLD(aSrc + 8 * 4096 + kOff, sBufE + aDstE + 512);
    }
#pragma unroll
    for (int mi = 0; mi < 4; mi++) af[mi] = *(const bf16x8*)&smem[bufE + aRow + mi * 1024 + colE0];
    bf[0] = *(const bf16x8*)&smem[bufE + bRow + 0 * 1024 + colE0];
    bf[1] = *(const bf16x8*)&smem[bufE + bRow + 1 * 1024 + colE0];
    __builtin_amdgcn_s_setprio(1);
#pragma unroll
    for (int mi = 0; mi < 4; mi++) {
      acc[mi][0] = __builtin_amdgcn_mfma_f32_16x16x32_bf16(af[mi], bf[0], acc[mi][0], 0, 0, 0);
      acc[mi][1] = __builtin_amdgcn_mfma_f32_16x16x32_bf16(af[mi], bf[1], acc[mi][1], 0, 0, 0);
    }
    __builtin_amdgcn_s_setprio(0);
    __builtin_amdgcn_s_barrier();
    // ---- phase 1: stage B(j0,j1) ; compute kk0, ni 2-3
    if (doStage) {
      GLD(bSrc + kOff, sBufE + bDstE);
      GLD(bSrc + 8 * 4096 + kOff, sBufE + bDstE + 512);
    }
    bf[2] = *(const bf16x8*)&smem[bufE + bRow + 2 * 1024 + colE0];
    bf[3] = *(const bf16x8*)&smem[bufE + bRow + 3 * 1024 + colE0];
    __builtin_amdgcn_s_setprio(1);
#pragma unroll
    for (int mi = 0; mi < 4; mi++) {
      acc[mi][2] = __builtin_amdgcn_mfma_f32_16x16x32_bf16(af[mi], bf[2], acc[mi][2], 0, 0, 0);
      acc[mi][3] = __builtin_amdgcn_mfma_f32_16x16x32_bf16(af[mi], bf[3], acc[mi][3], 0, 0, 0);
    }
    __builtin_amdgcn_s_setprio(0);
    __builtin_amdgcn_s_barrier();
    // ---- phase 2: stage B(j2,j3) ; compute kk1, ni 0-1
    if (doStage) {
      GLD(bSrc + 16 * 4096 + kOff, sBufE + bDstE + 1024);
      GLD(bSrc + 24 * 4096 + kOff, sBufE + bDstE + 1536);
    }
#pragma unroll
    for (int mi = 0; mi < 4; mi++) af[mi] = *(const bf16x8*)&smem[bufE + aRow + mi * 1024 + colE1];
    bf[0] = *(const bf16x8*)&smem[bufE + bRow + 0 * 1024 + colE1];
    bf[1] = *(const bf16x8*)&smem[bufE + bRow + 1 * 1024 + colE1];
    __builtin_amdgcn_s_setprio(1);
#pragma unroll
    for (int mi = 0; mi < 4; mi++) {
      acc[mi][0] = __builtin_amdgcn_mfma_f32_16x16x32_bf16(af[mi], bf[0], acc[mi][0], 0, 0, 0);
      acc[mi][1] = __builtin_amdgcn_mfma_f32_16x16x32_bf16(af[mi], bf[1], acc[mi][1], 0, 0, 0);
    }
    __builtin_amdgcn_s_setprio(0);
    __builtin_amdgcn_s_barrier();
    // ---- phase 3: compute kk1, ni 2-3
    bf[2] = *(const bf16x8*)&smem[bufE + bRow + 2 * 1024 + colE1];
    bf[3] = *(const bf16x8*)&smem[bufE + bRow + 3 * 1024 + colE1];
    __builtin_amdgcn_s_setprio(1);
#pragma unroll
    for (int mi = 0; mi < 4; mi++) {
      acc[mi][2] = __builtin_amdgcn_mfma_f32_16x16x32_bf16(af[mi], bf[2], acc[mi][2], 0, 0, 0);
      acc[mi][3] = __builtin_amdgcn_mfma_f32_16x16x32_bf16(af[mi], bf[3], acc[mi][3], 0, 0, 0);
    }
    __builtin_amdgcn_s_setprio(0);
    // ---- tile boundary: counted vmcnt, never drain in steady state
    if (t < 62) {
      asm volatile("s_waitcnt vmcnt(6)" ::: "memory");  // tile t+1 staged
    } else if (t == 62) {
      asm volatile("s_waitcnt vmcnt(0)" ::: "memory");  // last tile staged
    }
    if (t < 63) {
      __builtin_amdgcn_s_barrier();
      __builtin_amdgcn_sched_barrier(0);
    }
    bufE += 24576; if (bufE == 73728) bufE = 0;
    sBufE += 24576; if (sBufE == 73728) sBufE = 0;
    kOff += 64;
  }

  // Fused LSTM epilogue: acc[mi][gate][r] register-local per (row, hcol).
  const int hcol = (bn * 4 + wn) * 16 + laneRow;
  const float bI = bii[hcol] + bhi[hcol];
  const float bF = bif_[hcol] + bhf[hcol];
  const float bG = big_[hcol] + bhg[hcol];
  const float bO = bio_[hcol] + bho[hcol];
  const int rbase = bm * 128 + wm * 64 + lane16 * 4;
#pragma unroll
  for (int mi = 0; mi < 4; mi++) {
#pragma unroll
    for (int rr = 0; rr < 4; rr++) {
      const int row = rbase + mi * 16 + rr;
      const float ii = acc[mi][0][rr] + bI;
      const float ff = acc[mi][1][rr] + bF;
      const float gg = acc[mi][2][rr] + bG;
      const float oo = acc[mi][3][rr] + bO;
      const float iv = 1.f / (1.f + __expf(-ii));
      const float fv = 1.f / (1.f + __expf(-ff));
      const float gv = tanhf(gg);
      const float ov = 1.f / (1.f + __expf(-oo));
      const float cv = c[(size_t)row * 2048 + hcol];
      const float cn = fv * cv + iv * gv;
      const float hn = ov * tanhf(cn);
      out[(size_t)row * 2048 + hcol] = hn;
      out[(size_t)8388608 + (size_t)row * 2048 + hcol] = cn;
    }
  }
}

extern "C" void kernel_launch(void* const* d_in, const int* in_sizes, int n_in,
                              void* d_out, int out_size, void* d_ws, size_t ws_size,
                              hipStream_t stream) {
  const float* x = (const float*)d_in[0];
  const float* h = (const float*)d_in[1];
  const float* c = (const float*)d_in[2];
  const float* Wii = (const float*)d_in[3];  const float* bii = (const float*)d_in[4];
  const float* Wif = (const float*)d_in[5];  const float* bif_ = (const float*)d_in[6];
  const float* Wig = (const float*)d_in[7];  const float* big_ = (const float*)d_in[8];
  const float* Wio = (const float*)d_in[9];  const float* bio_ = (const float*)d_in[10];
  const float* Whi = (const float*)d_in[11]; const float* bhi = (const float*)d_in[12];
  const float* Whf = (const float*)d_in[13]; const float* bhf = (const float*)d_in[14];
  const float* Whg = (const float*)d_in[15]; const float* bhg = (const float*)d_in[16];
  const float* Who = (const float*)d_in[17]; const float* bho = (const float*)d_in[18];

  ushort* Abf = (ushort*)d_ws;                    // 4096*4096 bf16
  ushort* Wpk = Abf + (size_t)4096 * 4096;        // 8192*4096 bf16
  float* out = (float*)d_out;

  pack_a_kernel<<<2048, 256, 0, stream>>>((const float4*)x, (const float4*)h, (ushort4*)Abf);
  pack_w_kernel<<<2048, 256, 0, stream>>>(Wii, Wif, Wig, Wio, Whi, Whf, Whg, Who, (ushort4*)Wpk);
  lstm_gemm_kernel<<<1024, 512, 0, stream>>>(Abf, Wpk, c,
                                             bii, bif_, big_, bio_, bhi, bhf, bhg, bho, out);
}

// Round 3
// 330.583 us; speedup vs baseline: 1.4069x; 1.2309x over previous
//
#include <hip/hip_runtime.h>
#include <stdint.h>

typedef __attribute__((ext_vector_type(4))) float f32x4;
typedef __attribute__((ext_vector_type(8))) short bf16x8;

#define MFMA_BF16 __builtin_amdgcn_mfma_f32_16x16x32_bf16

__device__ __forceinline__ unsigned short f2bf(float f) {
  union { float f; uint32_t u; } a; a.f = f;
  uint32_t u = a.u;
  uint32_t r = (u + 0x7FFFu + ((u >> 16) & 1u)) >> 16;
  return (unsigned short)r;
}

// Pack [x | h] -> bf16 A[4096][4096] row-major (K = IN(2048) then H(2048))
__global__ void pack_a_kernel(const float4* __restrict__ x, const float4* __restrict__ hh,
                              ushort4* __restrict__ A) {
  const int total = 4096 * 1024;
  for (int q = blockIdx.x * blockDim.x + threadIdx.x; q < total; q += gridDim.x * blockDim.x) {
    int row = q >> 10, cq = q & 1023;
    float4 v = (cq < 512) ? x[row * 512 + cq] : hh[row * 512 + (cq - 512)];
    ushort4 o; o.x = f2bf(v.x); o.y = f2bf(v.y); o.z = f2bf(v.z); o.w = f2bf(v.w);
    A[q] = o;
  }
}

// Pack 8 weight mats -> bf16 Wp[8192][4096].
// Packed row p: bn=p>>8, r=p&255; half=r>>7, wn=(r>>5)&3, glow=(r>>4)&1, hlow=r&15
//   gate g = half*2+glow ; hcol H = bn*64 + wn*16 + hlow
// cols 0..2047 = Wx_g[H][:], 2048..4095 = Wh_g[H][:]
__global__ void pack_w_kernel(const float* __restrict__ Wii, const float* __restrict__ Wif,
                              const float* __restrict__ Wig, const float* __restrict__ Wio,
                              const float* __restrict__ Whi, const float* __restrict__ Whf,
                              const float* __restrict__ Whg, const float* __restrict__ Who,
                              ushort4* __restrict__ Wp) {
  const int total = 8192 * 1024;
  for (int q = blockIdx.x * blockDim.x + threadIdx.x; q < total; q += gridDim.x * blockDim.x) {
    int p = q >> 10, kq = q & 1023;
    int r = p & 255;
    int g = ((r >> 7) << 1) | ((r >> 4) & 1);
    int H = ((p >> 8) << 6) | (((r >> 5) & 3) << 4) | (r & 15);
    const float* src;
    if (kq < 512) src = (g == 0) ? Wii : (g == 1) ? Wif : (g == 2) ? Wig : Wio;
    else          src = (g == 0) ? Whi : (g == 1) ? Whf : (g == 2) ? Whg : Who;
    const float4 v = *(const float4*)&src[(size_t)H * 2048 + ((kq & 511) << 2)];
    ushort4 o; o.x = f2bf(v.x); o.y = f2bf(v.y); o.z = f2bf(v.z); o.w = f2bf(v.w);
    Wp[q] = o;
  }
}

// 256x256 tile, BK=64, 8 waves (2Mx4N), per-wave 128x64, 4 phases/tile,
// 2-tile LDS dbuf (128 KiB) with half-tile ring staging + counted vmcnt.
#define STG(srcbase, jj, koff, dstE)                                                        \
  __builtin_amdgcn_global_load_lds(                                                        \
      (const __attribute__((address_space(1))) void*)((srcbase) + (size_t)(jj)*262144 + (koff)), \
      (__attribute__((address_space(3))) void*)(&smem[(dstE) + (jj)*4096]), 16, 0, 0)

__global__ __launch_bounds__(512, 1)
void lstm_gemm_kernel(const ushort* __restrict__ A, const ushort* __restrict__ Wp,
                      const float* __restrict__ c,
                      const float* __restrict__ bii, const float* __restrict__ bif_,
                      const float* __restrict__ big_, const float* __restrict__ bio_,
                      const float* __restrict__ bhi, const float* __restrict__ bhf,
                      const float* __restrict__ bhg, const float* __restrict__ bho,
                      float* __restrict__ out) {
  __shared__ ushort smem[65536];  // 2 bufs x (A 256x64 + B 256x64) bf16 = 128 KiB
  const int tid = threadIdx.x;
  const int lane = tid & 63, w = tid >> 6;
  const int wm = w >> 2, wn = w & 3;

  // XCD-aware bijective swizzle (512 blocks, 8 XCDs): each XCD gets 2 bm-panels
  const int bid = blockIdx.x;
  const int wg = (bid & 7) * 64 + (bid >> 3);
  const int bm = wg >> 5, bn = wg & 31;

  const int laneRow = lane & 15, lane16 = lane >> 4;
  const int lr7 = laneRow & 7;
  const int colE0 = (lane16 ^ lr7) << 3;         // elem offset within row, kk=0
  const int colE1 = ((4 + lane16) ^ lr7) << 3;   // kk=1

  // Staging: per inst, lane l -> LDS row +(l>>3), phys slot (l&7); slot s at row r
  // holds logical chunk s^(r&7) -> pre-swizzled global source chunk.
  const int srow = w * 8 + (lane >> 3);
  const int chunkOff = ((lane & 7) ^ (lane >> 3)) << 3;
  const ushort* aSrc = A + (size_t)(bm * 256 + srow) * 4096 + chunkOff;
  const ushort* bSrc = Wp + (size_t)(bn * 256 + srow) * 4096 + chunkOff;
  const int aDstW = w * 512;           // + buf + j*4096
  const int bDstW = 16384 + w * 512;

  const int aBase = (wm * 64 + laneRow) * 64;           // + buf + miq*8192 + m*1024 + colE
  const int bBase = 16384 + (wn * 32 + laneRow) * 64;   // + buf + (ni>>1)*8192 + (ni&1)*1024 + colE

  f32x4 acc[8][4];
#pragma unroll
  for (int i = 0; i < 8; i++)
#pragma unroll
    for (int j = 0; j < 4; j++) acc[i][j] = (f32x4){0.f, 0.f, 0.f, 0.f};

  // Prologue: T0 fully (A0,B0,A1,B1), T1 first half (A0,B0). 12 insts/wave.
  STG(aSrc, 0, 0, aDstW); STG(aSrc, 1, 0, aDstW);
  STG(bSrc, 0, 0, bDstW); STG(bSrc, 1, 0, bDstW);
  STG(aSrc, 2, 0, aDstW); STG(aSrc, 3, 0, aDstW);
  STG(bSrc, 2, 0, bDstW); STG(bSrc, 3, 0, bDstW);
  STG(aSrc, 0, 64, 32768 + aDstW); STG(aSrc, 1, 64, 32768 + aDstW);
  STG(bSrc, 0, 64, 32768 + bDstW); STG(bSrc, 1, 64, 32768 + bDstW);
  asm volatile("s_waitcnt vmcnt(8)" ::: "memory");  // T0:A0,B0 resident
  __builtin_amdgcn_s_barrier();
  __builtin_amdgcn_sched_barrier(0);

#pragma unroll 1
  for (int T = 0; T < 64; ++T) {
    const int bufE = (T & 1) << 15;
    const int obufE = bufE ^ 32768;
    const int kN = (T + 1) << 6;
    const int kN2 = (T + 2) << 6;
    bf16x8 af[4][2], bf[4][2];

    // ===== phase 0: miq0,niq0  (ds: af(miq0)x8 + bf(0,1)x4; stage (T+1):A1)
#pragma unroll
    for (int m = 0; m < 4; ++m) {
      af[m][0] = *(const bf16x8*)&smem[bufE + aBase + m * 1024 + colE0];
      af[m][1] = *(const bf16x8*)&smem[bufE + aBase + m * 1024 + colE1];
    }
#pragma unroll
    for (int n = 0; n < 2; ++n) {
      bf[n][0] = *(const bf16x8*)&smem[bufE + bBase + n * 1024 + colE0];
      bf[n][1] = *(const bf16x8*)&smem[bufE + bBase + n * 1024 + colE1];
    }
    if (T < 63) { STG(aSrc, 2, kN, obufE + aDstW); STG(aSrc, 3, kN, obufE + aDstW); }
    __builtin_amdgcn_s_barrier();
    asm volatile("s_waitcnt lgkmcnt(0)" ::: "memory");
    __builtin_amdgcn_sched_barrier(0);
    __builtin_amdgcn_s_setprio(1);
#pragma unroll
    for (int m = 0; m < 4; ++m)
#pragma unroll
      for (int n = 0; n < 2; ++n) {
        acc[m][n] = MFMA_BF16(af[m][0], bf[n][0], acc[m][n], 0, 0, 0);
        acc[m][n] = MFMA_BF16(af[m][1], bf[n][1], acc[m][n], 0, 0, 0);
      }
    __builtin_amdgcn_s_setprio(0);
    if (T < 63) asm volatile("s_waitcnt vmcnt(6)" ::: "memory");   // T:B1 (and A1) resident
    else        asm volatile("s_waitcnt vmcnt(0)" ::: "memory");
    __builtin_amdgcn_s_barrier();

    // ===== phase 1: miq0,niq1  (ds: bf(2,3)x4; stage (T+1):B1)
#pragma unroll
    for (int n = 0; n < 2; ++n) {
      bf[2 + n][0] = *(const bf16x8*)&smem[bufE + bBase + 8192 + n * 1024 + colE0];
      bf[2 + n][1] = *(const bf16x8*)&smem[bufE + bBase + 8192 + n * 1024 + colE1];
    }
    if (T < 63) { STG(bSrc, 2, kN, obufE + bDstW); STG(bSrc, 3, kN, obufE + bDstW); }
    __builtin_amdgcn_s_barrier();
    asm volatile("s_waitcnt lgkmcnt(0)" ::: "memory");
    __builtin_amdgcn_sched_barrier(0);
    __builtin_amdgcn_s_setprio(1);
#pragma unroll
    for (int m = 0; m < 4; ++m)
#pragma unroll
      for (int n = 0; n < 2; ++n) {
        acc[m][2 + n] = MFMA_BF16(af[m][0], bf[2 + n][0], acc[m][2 + n], 0, 0, 0);
        acc[m][2 + n] = MFMA_BF16(af[m][1], bf[2 + n][1], acc[m][2 + n], 0, 0, 0);
      }
    __builtin_amdgcn_s_setprio(0);
    __builtin_amdgcn_s_barrier();

    // ===== phase 2: miq1,niq0  (ds: af(miq1)x8; stage (T+2):A0)
#pragma unroll
    for (int m = 0; m < 4; ++m) {
      af[m][0] = *(const bf16x8*)&smem[bufE + aBase + 8192 + m * 1024 + colE0];
      af[m][1] = *(const bf16x8*)&smem[bufE + aBase + 8192 + m * 1024 + colE1];
    }
    if (T < 62) { STG(aSrc, 0, kN2, bufE + aDstW); STG(aSrc, 1, kN2, bufE + aDstW); }
    __builtin_amdgcn_s_barrier();
    asm volatile("s_waitcnt lgkmcnt(0)" ::: "memory");
    __builtin_amdgcn_sched_barrier(0);
    __builtin_amdgcn_s_setprio(1);
#pragma unroll
    for (int m = 0; m < 4; ++m)
#pragma unroll
      for (int n = 0; n < 2; ++n) {
        acc[4 + m][n] = MFMA_BF16(af[m][0], bf[n][0], acc[4 + m][n], 0, 0, 0);
        acc[4 + m][n] = MFMA_BF16(af[m][1], bf[n][1], acc[4 + m][n], 0, 0, 0);
      }
    __builtin_amdgcn_s_setprio(0);
    __builtin_amdgcn_s_barrier();

    // ===== phase 3: miq1,niq1  (no ds; stage (T+2):B0)
    if (T < 62) { STG(bSrc, 0, kN2, bufE + bDstW); STG(bSrc, 1, kN2, bufE + bDstW); }
    __builtin_amdgcn_s_barrier();
    __builtin_amdgcn_s_setprio(1);
#pragma unroll
    for (int m = 0; m < 4; ++m)
#pragma unroll
      for (int n = 0; n < 2; ++n) {
        acc[4 + m][2 + n] = MFMA_BF16(af[m][0], bf[2 + n][0], acc[4 + m][2 + n], 0, 0, 0);
        acc[4 + m][2 + n] = MFMA_BF16(af[m][1], bf[2 + n][1], acc[4 + m][2 + n], 0, 0, 0);
      }
    __builtin_amdgcn_s_setprio(0);
    if (T < 62)      asm volatile("s_waitcnt vmcnt(8)" ::: "memory");  // (T+1):A0,B0 resident
    else if (T == 62) asm volatile("s_waitcnt vmcnt(4)" ::: "memory");
    __builtin_amdgcn_s_barrier();
  }

  // Fused LSTM epilogue: acc[mi][gate][rr] register-local per (row, hcol).
  const int hcol = bn * 64 + wn * 16 + laneRow;
  const float bI = bii[hcol] + bhi[hcol];
  const float bF = bif_[hcol] + bhf[hcol];
  const float bG = big_[hcol] + bhg[hcol];
  const float bO = bio_[hcol] + bho[hcol];
#pragma unroll
  for (int mi = 0; mi < 8; ++mi) {
    const int rowBase = bm * 256 + (mi >> 2) * 128 + wm * 64 + (mi & 3) * 16 + lane16 * 4;
#pragma unroll
    for (int rr = 0; rr < 4; ++rr) {
      const int row = rowBase + rr;
      const float ii = acc[mi][0][rr] + bI;
      const float ff = acc[mi][1][rr] + bF;
      const float gg = acc[mi][2][rr] + bG;
      const float oo = acc[mi][3][rr] + bO;
      const float iv = 1.f / (1.f + __expf(-ii));
      const float fv = 1.f / (1.f + __expf(-ff));
      const float gv = tanhf(gg);
      const float ov = 1.f / (1.f + __expf(-oo));
      const float cv = c[(size_t)row * 2048 + hcol];
      const float cn = fv * cv + iv * gv;
      const float hn = ov * tanhf(cn);
      out[(size_t)row * 2048 + hcol] = hn;
      out[(size_t)8388608 + (size_t)row * 2048 + hcol] = cn;
    }
  }
}

extern "C" void kernel_launch(void* const* d_in, const int* in_sizes, int n_in,
                              void* d_out, int out_size, void* d_ws, size_t ws_size,
                              hipStream_t stream) {
  const float* x = (const float*)d_in[0];
  const float* h = (const float*)d_in[1];
  const float* c = (const float*)d_in[2];
  const float* Wii = (const float*)d_in[3];  const float* bii = (const float*)d_in[4];
  const float* Wif = (const float*)d_in[5];  const float* bif_ = (const float*)d_in[6];
  const float* Wig = (const float*)d_in[7];  const float* big_ = (const float*)d_in[8];
  const float* Wio = (const float*)d_in[9];  const float* bio_ = (const float*)d_in[10];
  const float* Whi = (const float*)d_in[11]; const float* bhi = (const float*)d_in[12];
  const float* Whf = (const float*)d_in[13]; const float* bhf = (const float*)d_in[14];
  const float* Whg = (const float*)d_in[15]; const float* bhg = (const float*)d_in[16];
  const float* Who = (const float*)d_in[17]; const float* bho = (const float*)d_in[18];

  ushort* Abf = (ushort*)d_ws;                    // 4096*4096 bf16
  ushort* Wpk = Abf + (size_t)4096 * 4096;        // 8192*4096 bf16
  float* out = (float*)d_out;

  pack_a_kernel<<<2048, 256, 0, stream>>>((const float4*)x, (const float4*)h, (ushort4*)Abf);
  pack_w_kernel<<<2048, 256, 0, stream>>>(Wii, Wif, Wig, Wio, Whi, Whf, Whg, Who, (ushort4*)Wpk);
  lstm_gemm_kernel<<<512, 512, 0, stream>>>(Abf, Wpk, c,
                                            bii, bif_, big_, bio_, bhi, bhf, bhg, bho, out);
}